// Round 11
// baseline (222.077 us; speedup 1.0000x reference)
//
#include <hip/hip_runtime.h>
#include <math.h>

// CARE position encoding, Cl(5,0,0), MV=32.
// out = R x R~ with R = cos(theta) + sinc(theta)*Bf, Bf = 0.5*(pos*B_x + 0.01*pos*B_y)
// Cayley structure is deterministic -> hardcoded at compile time.

#define MV 32
#define NB 10
#define NR 11

// clang-native vector type: required by __builtin_nontemporal_* (HIP float4 is rejected)
typedef float v4f __attribute__((ext_vector_type(4)));

__host__ __device__ constexpr int popc_c(unsigned v) {
    int c = 0;
    while (v) { c += (int)(v & 1u); v >>= 1; }
    return c;
}

// sign of basis-blade product: C[a, b, a^b]
__host__ __device__ constexpr float csign(int a, int b) {
    int s = 0;
    unsigned aa = ((unsigned)a) >> 1;
    while (aa) { s += popc_c(aa & (unsigned)b); aa >>= 1; }
    return (s & 1) ? -1.0f : 1.0f;
}

// bivector blade indices (popcount == 2) among 0..31
__device__ constexpr int BIV[NB]  = {3, 5, 6, 9, 10, 12, 17, 18, 20, 24};
// rotor nonzero indices: scalar + bivectors
__device__ constexpr int RIDX[NR] = {0, 3, 5, 6, 9, 10, 12, 17, 18, 20, 24};

__global__ __launch_bounds__(256) void care_kernel(
    const float* __restrict__ x,
    const int*   __restrict__ pos,
    const float* __restrict__ Bx,
    const float* __restrict__ By,
    float*       __restrict__ out,
    int n_pos)
{
    int p = blockIdx.x * blockDim.x + threadIdx.x;
    if (p >= n_pos) return;

    // ---- rotor scalars ----
    int pp = pos[p];
    pp = pp < 0 ? 0 : (pp > 8191 ? 8191 : pp);
    float posf = (float)pp;
    float thx = posf;           // freqs[0] = 1.0
    float thy = posf * 0.01f;   // freqs[1] = 0.01

    float bf[NB];
    float bb = 0.f;
#pragma unroll
    for (int t = 0; t < NB; t++) {
        const int i = BIV[t];
        float v = 0.5f * (thx * Bx[i] + thy * By[i]);
        bf[t] = v;
        // BB scalar part: sum bf_i^2 * C[i,i,0]  (== -1 for all bivectors here)
        if (csign(i, i) > 0.f) bb = fmaf(v, v, bb);
        else                   bb = fmaf(-v, v, bb);
    }
    float theta_sq = fmaxf(-bb, 0.f);
    float theta = sqrtf(theta_sq + 1e-16f);
    bool is_small = theta_sq < 1e-10f;
    float theta_safe = theta + ((theta < 1e-10f) ? 1e-10f : 0.f);
    float s, c;
    sincosf(theta_safe, &s, &c);
    float sinc = is_small ? 1.f : (s / theta_safe);
    float cosv = is_small ? 1.f : c;

    float r[NR];
    r[0] = cosv;
#pragma unroll
    for (int t = 0; t < NB; t++) r[1 + t] = sinc * bf[t];

    // ---- load x row (128 B contiguous per thread; cached — intra-thread line reuse) ----
    float xv[MV];
    const v4f* xr = reinterpret_cast<const v4f*>(x + (size_t)p * MV);
#pragma unroll
    for (int k = 0; k < 8; k++) {
        v4f v = xr[k];
        xv[4*k+0] = v.x; xv[4*k+1] = v.y; xv[4*k+2] = v.z; xv[4*k+3] = v.w;
    }

    // ---- stage 1: Rx = gp(rotor, x) ----
    float rx[MV];
#pragma unroll
    for (int l = 0; l < MV; l++) {
        float acc = 0.f;
#pragma unroll
        for (int t = 0; t < NR; t++) {
            const int i = RIDX[t];
            const int j = i ^ l;             // x index; i^j == l
            const float sg = csign(i, j);
            acc = (sg > 0.f) ? fmaf(r[t], xv[j], acc)
                             : fmaf(-r[t], xv[j], acc);
        }
        rx[l] = acc;
    }

    // ---- stage 2: out = gp(Rx, R_rev), R_rev = r0 - bivector parts ----
    v4f* orow = reinterpret_cast<v4f*>(out + (size_t)p * MV);
#pragma unroll
    for (int g = 0; g < 8; g++) {
        v4f ov;
#pragma unroll
        for (int q = 0; q < 4; q++) {
            const int l = 4 * g + q;
            float acc = 0.f;
#pragma unroll
            for (int t = 0; t < NR; t++) {
                const int m = RIDX[t];
                const int j = l ^ m;         // Rx index; j^m == l
                // reverse negates bivector components (t>0)
                const float sg = csign(j, m) * (t == 0 ? 1.f : -1.f);
                acc = (sg > 0.f) ? fmaf(r[t], rx[j], acc)
                                 : fmaf(-r[t], rx[j], acc);
            }
            ov[q] = acc;
        }
        __builtin_nontemporal_store(ov, &orow[g]);
    }
}

extern "C" void kernel_launch(void* const* d_in, const int* in_sizes, int n_in,
                              void* d_out, int out_size, void* d_ws, size_t ws_size,
                              hipStream_t stream) {
    const float* x   = (const float*)d_in[0];
    const int*   pos = (const int*)  d_in[1];
    const float* Bx  = (const float*)d_in[2];
    const float* By  = (const float*)d_in[3];
    // d_in[4] = cayley (hardcoded), d_in[5] = biv_mask (hardcoded)
    float* out = (float*)d_out;

    int n_pos = in_sizes[0] / MV;  // 32*8192 = 262144 positions
    int block = 256;
    int grid = (n_pos + block - 1) / block;
    care_kernel<<<grid, block, 0, stream>>>(x, pos, Bx, By, out, n_pos);
}